// Round 10
// baseline (1889.187 us; speedup 1.0000x reference)
//
#include <hip/hip_runtime.h>
#include <math.h>

typedef unsigned short ushort_t;
typedef __attribute__((ext_vector_type(4))) float floatx4;
typedef __attribute__((ext_vector_type(8))) short shortx8;
typedef __attribute__((ext_vector_type(8))) unsigned short ushortx8;

__device__ __forceinline__ float bf2f(ushort_t h) {
    union { unsigned u; float f; } x; x.u = ((unsigned)h) << 16; return x.f;
}
__device__ __forceinline__ ushort_t f2bf(float f) {
    union { float f; unsigned u; } x; x.f = f;
    unsigned r = x.u + 0x7fffu + ((x.u >> 16) & 1u);
    return (ushort_t)(r >> 16);
}
__device__ __forceinline__ float rdIn(const void* p, size_t i, int f32) {
    return f32 ? ((const float*)p)[i] : bf2f(((const ushort_t*)p)[i]);
}
// branch-free GELU: erf via Abramowitz-Stegun 7.1.26 (|erf err| <= 1.5e-7)
__device__ __forceinline__ float gelu_f(float v) {
    float z = fabsf(v) * 0.70710678118654752f;
    float t = __builtin_amdgcn_rcpf(1.0f + 0.3275911f * z);
    float p = 1.061405429f;
    p = p * t - 1.453152027f;
    p = p * t + 1.421413741f;
    p = p * t - 0.284496736f;
    p = p * t + 0.254829592f;
    p = p * t;
    float er = 1.0f - p * __expf(-z * z);
    er = copysignf(er, v);
    return 0.5f * v * (1.0f + er);
}

// ---------------- dtype detect: bf16 vs fp32 --------------------------------
__global__ __launch_bounds__(256) void detect_kernel(const ushort_t* __restrict__ x,
                                                     int* __restrict__ flag) {
    __shared__ int cnt;
    if (threadIdx.x == 0) cnt = 0;
    __syncthreads();
    ushort_t v = x[threadIdx.x];
    int e = (v >> 7) & 0xff;
    int ok = (e >= 100 && e <= 150) || (v == 0);
    atomicAdd(&cnt, ok);
    __syncthreads();
    if (threadIdx.x == 0) flag[0] = (cnt >= 240) ? 0 : 1;   // 0=bf16, 1=fp32
}

// ---------------- prep: x [2,4095,512] raw -> Xp [2,4096,512] bf16 ----------
__global__ __launch_bounds__(256) void prep_kernel(const void* __restrict__ x,
                                                   ushort_t* __restrict__ Xp,
                                                   const int* __restrict__ flag) {
    const int f32 = flag[0];
    int i = blockIdx.x * 256 + threadIdx.x;
    int e = i * 8;
    int s = (e >> 9) & 4095;
    int b = e >> 21;
    ushortx8 val = {0, 0, 0, 0, 0, 0, 0, 0};
    if (s < 4095) {
        size_t src = ((size_t)(b * 4095 + s) << 9) + (e & 511);
        if (f32) {
            const float* p = (const float*)x + src;
            floatx4 a = *(const floatx4*)p;
            floatx4 c = *(const floatx4*)(p + 4);
            val[0] = f2bf(a[0]); val[1] = f2bf(a[1]); val[2] = f2bf(a[2]); val[3] = f2bf(a[3]);
            val[4] = f2bf(c[0]); val[5] = f2bf(c[1]); val[6] = f2bf(c[2]); val[7] = f2bf(c[3]);
        } else {
            val = *(const ushortx8*)((const ushort_t*)x + src);
        }
    }
    *(ushortx8*)&Xp[e] = val;
}

// ---------------- transpose raw weight [R,C] -> bf16 [C,R] ------------------
__global__ __launch_bounds__(256) void transpose_kernel(
    const void* __restrict__ in0, const void* __restrict__ in1,
    const void* __restrict__ in2, ushort_t* __restrict__ out,
    int R, int C, const int* __restrict__ flag) {
    const int f32 = flag[0];
    const int z = blockIdx.z;
    const void* in = (z == 0) ? in0 : (z == 1) ? in1 : in2;
    __shared__ ushort_t tile[32][33];
    int c0 = blockIdx.x * 32, r0 = blockIdx.y * 32;
    int tx = threadIdx.x & 31, ty = threadIdx.x >> 5;
#pragma unroll
    for (int i = 0; i < 4; i++) {
        size_t idx = (size_t)(r0 + ty + 8 * i) * C + c0 + tx;
        tile[ty + 8 * i][tx] = f32 ? f2bf(((const float*)in)[idx])
                                   : ((const ushort_t*)in)[idx];
    }
    __syncthreads();
#pragma unroll
    for (int i = 0; i < 4; i++)
        out[(size_t)z * R * C + (size_t)(c0 + ty + 8 * i) * R + r0 + tx] =
            tile[tx][ty + 8 * i];
}

// ---------------- GEMM epilogue (shared) ------------------------------------
__device__ __forceinline__ void gemm_epilogue(
    float v, int m, int n, int N, float scale, int epi,
    const void* bias0, const void* bias1, const void* bias2,
    void* outp, const ushort_t* resid, int f32) {
    if (epi == 3) {
        int idx = n >> 9, off = n & 511;
        const void* bp = (idx == 0) ? bias0 : (idx == 1) ? bias1 : bias2;
        float bb = rdIn(bp, off, f32);
        float sc = (idx == 0) ? scale : 1.0f;
        ((ushort_t*)outp)[(size_t)idx * 4194304 + (size_t)m * 512 + off] =
            f2bf((v + bb) * sc);
    } else if (epi == 1) {
        v += rdIn(bias0, n, f32);
        ((ushort_t*)outp)[(size_t)m * N + n] = f2bf(gelu_f(v));
    } else {
        int bb2 = m >> 12, s = m & 4095;
        if (s < 4095) {
            v += rdIn(bias0, n, f32) + bf2f(resid[(size_t)m * N + n]);
            size_t oidx = ((size_t)bb2 * 4095 + s) * (size_t)N + n;
            if (f32) ((float*)outp)[oidx] = v;
            else     ((ushort_t*)outp)[oidx] = f2bf(v);
        }
    }
}

// ---------------- GEMM: 128xTBN tile, reg-staged software pipeline ----------
// Global->VGPR loads (NOT global_load_lds) are not drained by __syncthreads:
// vmcnt waits attach only to the consuming ds_write. Depth-3 pipeline:
// tile k computes from LDS[k&1]; tile k+1 sits in regs S[k&1] and is ds_written
// to LDS[~k&1] this iter; tile k+3's load is issued into the freed S[k&1].
// So each ds_write waits on a load issued 2 full iterations earlier.
#define BM 128
#define BK 32

template<int TBN>
__global__ __launch_bounds__(256) void gemm_bt_kernel(
    const ushort_t* __restrict__ A, const ushort_t* __restrict__ Bt,
    const void* __restrict__ bias0, const void* __restrict__ bias1,
    const void* __restrict__ bias2, void* outp,
    int M, int N, int K, float scale, int epi,
    const ushort_t* __restrict__ resid, const int* __restrict__ flag) {
    constexpr int TN = TBN / 32;
    const int f32 = flag[0];
    __shared__ __align__(16) ushort_t As[2][BM][BK];
    __shared__ __align__(16) ushort_t Bs[2][TBN][BK];
    const int m0 = blockIdx.x * BM, n0 = blockIdx.y * TBN;
    const int t = threadIdx.x;
    const int lane = t & 63, wave = t >> 6;
    const int wr = wave >> 1, wc = wave & 1;
    const int quad = lane >> 4, l16 = lane & 15;

    // staging maps: A 8KB/tile -> 32B/thread (2 chunks); B 8KB or 4KB
    const int ar = t >> 1, ac = (t & 1) * 16;                 // A row, elem col
    const int br = (TBN == 128) ? (t >> 1) : (t >> 2);
    const int bc = (TBN == 128) ? (t & 1) * 16 : (t & 3) * 8;
    const ushort_t* AgBase = A + (size_t)(m0 + ar) * K + ac;
    const ushort_t* BgBase = Bt + (size_t)(n0 + br) * K + bc;

    shortx8 sa[2][2], sb[2][2];
#define LOAD_TILE(kt, s)                                                  \
    do {                                                                  \
        const ushort_t* Ag_ = AgBase + (kt) * BK;                         \
        sa[s][0] = *(const shortx8*)(Ag_);                                \
        sa[s][1] = *(const shortx8*)(Ag_ + 8);                            \
        const ushort_t* Bg_ = BgBase + (kt) * BK;                         \
        sb[s][0] = *(const shortx8*)(Bg_);                                \
        if (TBN == 128) sb[s][1] = *(const shortx8*)(Bg_ + 8);            \
    } while (0)
#define WRITE_TILE(buf, s)                                                \
    do {                                                                  \
        *(shortx8*)&As[buf][ar][ac] = sa[s][0];                           \
        *(shortx8*)&As[buf][ar][ac + 8] = sa[s][1];                       \
        *(shortx8*)&Bs[buf][br][bc] = sb[s][0];                           \
        if (TBN == 128) *(shortx8*)&Bs[buf][br][bc + 8] = sb[s][1];       \
    } while (0)

    floatx4 acc[4][TN];
#pragma unroll
    for (int i = 0; i < 4; i++)
#pragma unroll
        for (int j = 0; j < TN; j++)
#pragma unroll
            for (int r = 0; r < 4; r++) acc[i][j][r] = 0.f;

    const int KT = K / BK;     // >= 16 in all our calls
    // prologue: tile0 -> S1 -> LDS0; tile1 -> S0; tile2 -> S1
    LOAD_TILE(0, 1);
    LOAD_TILE(1, 0);
    WRITE_TILE(0, 1);          // waits vmcnt for S1 only
    LOAD_TILE(2, 1);

    for (int kt = 0; kt < KT; kt++) {
        __syncthreads();       // LDS[kt&1] = tile kt ready; LDS[nb] free
        const int cb = kt & 1, nb = cb ^ 1, ss = kt & 1;
        if (kt + 1 < KT) WRITE_TILE(nb, ss);        // tile kt+1 (load 2 iters old)
        if (kt + 3 < KT) LOAD_TILE(kt + 3, ss);     // reuse freed reg set
        shortx8 af[4], bfr[TN];
#pragma unroll
        for (int tm = 0; tm < 4; tm++)
            af[tm] = *(const shortx8*)&As[cb][wr * 64 + tm * 16 + l16][quad * 8];
#pragma unroll
        for (int tn = 0; tn < TN; tn++)
            bfr[tn] = *(const shortx8*)&Bs[cb][wc * (TBN / 2) + tn * 16 + l16][quad * 8];
#pragma unroll
        for (int tm = 0; tm < 4; tm++)
#pragma unroll
            for (int tn = 0; tn < TN; tn++)
                acc[tm][tn] = __builtin_amdgcn_mfma_f32_16x16x32_bf16(
                    af[tm], bfr[tn], acc[tm][tn], 0, 0, 0);
    }
#undef LOAD_TILE
#undef WRITE_TILE

#pragma unroll
    for (int tm = 0; tm < 4; tm++)
#pragma unroll
        for (int tn = 0; tn < TN; tn++)
#pragma unroll
            for (int r = 0; r < 4; r++)
                gemm_epilogue(acc[tm][tn][r],
                              m0 + wr * 64 + tm * 16 + quad * 4 + r,
                              n0 + wc * (TBN / 2) + tn * 16 + l16,
                              N, scale, epi, bias0, bias1, bias2, outp, resid, f32);
}

// ---------------- MFMA windowed attention + global key ----------------------
#define ALD 344

__global__ __launch_bounds__(256) void attn_mfma_kernel(
    ushort_t* Q, const ushort_t* __restrict__ Kx, const ushort_t* __restrict__ Vx) {
    __shared__ ushort_t Pl[64][ALD];
    __shared__ ushort_t Vt[2][64][40];
    __shared__ float pgl[64];

    const int t = threadIdx.x;
    const int lane = t & 63, w = t >> 6;
    const int l16 = lane & 15, quad = lane >> 4;
    const int bid = blockIdx.x;
    const int qt = bid & 63;
    const int h = (bid >> 6) & 7;
    const int b = bid >> 9;
    const int q0 = qt * 64;
    const int jmin = q0 - 128;
    const size_t base = ((size_t)b * 4096) * 512 + (size_t)h * 64;

    const int qw = q0 + w * 16;
    const int lo = qw - 128, hi = qw + 15 + 128;

    shortx8 qf0, qf1;
    {
        const ushort_t* qp = Q + base + (size_t)(qw + l16) * 512 + quad * 8;
        qf0 = *(const shortx8*)(qp);
        qf1 = *(const shortx8*)(qp + 32);
    }

    floatx4 s[21];
#pragma unroll
    for (int i = 0; i < 21; i++)
#pragma unroll
        for (int r = 0; r < 4; r++) s[i][r] = 0.f;

#pragma unroll
    for (int tt = 0; tt < 20; tt++) {
        int jt = jmin + tt * 16;
        if (jt + 15 < lo || jt > hi) continue;
        int key = jt + l16;
        int kcl = min(max(key, 0), 4094);
        const ushort_t* kp = Kx + base + (size_t)kcl * 512 + quad * 8;
        shortx8 k0 = *(const shortx8*)(kp);
        shortx8 k1 = *(const shortx8*)(kp + 32);
        s[tt] = __builtin_amdgcn_mfma_f32_16x16x32_bf16(qf0, k0, s[tt], 0, 0, 0);
        s[tt] = __builtin_amdgcn_mfma_f32_16x16x32_bf16(qf1, k1, s[tt], 0, 0, 0);
    }
    {
        const ushort_t* kp = Kx + base + (size_t)4095 * 512 + quad * 8;
        shortx8 k0 = *(const shortx8*)(kp);
        shortx8 k1 = *(const shortx8*)(kp + 32);
        s[20] = __builtin_amdgcn_mfma_f32_16x16x32_bf16(qf0, k0, s[20], 0, 0, 0);
        s[20] = __builtin_amdgcn_mfma_f32_16x16x32_bf16(qf1, k1, s[20], 0, 0, 0);
    }

#pragma unroll
    for (int tt = 0; tt < 20; tt++) {
        int j = jmin + tt * 16 + l16;
        bool okj = (j >= 0) && (j <= 4094);
#pragma unroll
        for (int r = 0; r < 4; r++) {
            int q = qw + quad * 4 + r;
            bool ok = okj && (j - q <= 128) && (q - j <= 128);
            if (!ok) s[tt][r] = -1e30f;
        }
    }
    if (l16 != 0) {
#pragma unroll
        for (int r = 0; r < 4; r++) s[20][r] = -1e30f;
    }

    floatx4 mx = s[0];
#pragma unroll
    for (int tt = 1; tt < 21; tt++)
#pragma unroll
        for (int r = 0; r < 4; r++) mx[r] = fmaxf(mx[r], s[tt][r]);
#pragma unroll
    for (int off = 1; off < 16; off <<= 1)
#pragma unroll
        for (int r = 0; r < 4; r++) mx[r] = fmaxf(mx[r], __shfl_xor(mx[r], off, 64));

    floatx4 sum;
#pragma unroll
    for (int r = 0; r < 4; r++) sum[r] = 0.f;
#pragma unroll
    for (int tt = 0; tt < 21; tt++)
#pragma unroll
        for (int r = 0; r < 4; r++) {
            float e = __expf(s[tt][r] - mx[r]);
            s[tt][r] = e;
            sum[r] += e;
        }
#pragma unroll
    for (int off = 1; off < 16; off <<= 1)
#pragma unroll
        for (int r = 0; r < 4; r++) sum[r] += __shfl_xor(sum[r], off, 64);

    floatx4 inv;
#pragma unroll
    for (int r = 0; r < 4; r++) inv[r] = 1.f / sum[r];

#pragma unroll
    for (int tt = 0; tt < 20; tt++)
#pragma unroll
        for (int r = 0; r < 4; r++)
            Pl[w * 16 + quad * 4 + r][tt * 16 + l16] = f2bf(s[tt][r]);
    if (l16 == 0) {
#pragma unroll
        for (int r = 0; r < 4; r++) pgl[w * 16 + quad * 4 + r] = s[20][r];
    }

    floatx4 o[4];
#pragma unroll
    for (int nt = 0; nt < 4; nt++)
#pragma unroll
        for (int r = 0; r < 4; r++) o[nt][r] = 0.f;

    const int ck = t & 31, cd = t >> 5;
    ushortx8 vreg;
    {
        int row = min(max(jmin + ck, 0), 4095);
        vreg = *(const ushortx8*)&Vx[base + (size_t)row * 512 + cd * 8];
    }
    for (int c = 0; c < 10; c++) {
#pragma unroll
        for (int e = 0; e < 8; e++) Vt[c & 1][cd * 8 + e][ck] = vreg[e];
        if (c < 9) {
            int row = min(max(jmin + (c + 1) * 32 + ck, 0), 4095);
            vreg = *(const ushortx8*)&Vx[base + (size_t)row * 512 + cd * 8];
        }
        __syncthreads();
        int jc = jmin + c * 32;
        if (jc + 31 >= lo && jc <= hi) {
            shortx8 pf = *(const shortx8*)&Pl[w * 16 + l16][c * 32 + quad * 8];
#pragma unroll
            for (int nt = 0; nt < 4; nt++) {
                shortx8 vf = *(const shortx8*)&Vt[c & 1][nt * 16 + l16][quad * 8];
                o[nt] = __builtin_amdgcn_mfma_f32_16x16x32_bf16(pf, vf, o[nt], 0, 0, 0);
            }
        }
    }

#pragma unroll
    for (int nt = 0; nt < 4; nt++) {
        float vg = bf2f(Vx[base + (size_t)4095 * 512 + nt * 16 + l16]);
#pragma unroll
        for (int r = 0; r < 4; r++) {
            float pg = pgl[w * 16 + quad * 4 + r];
            float val = (o[nt][r] + pg * vg) * inv[r];
            Q[base + (size_t)(qw + quad * 4 + r) * 512 + nt * 16 + l16] = f2bf(val);
        }
    }
}

// ---------------- residual + LayerNorm, in-place on hio ---------------------
__global__ __launch_bounds__(256) void ln_kernel(
    const void* __restrict__ x, ushort_t* hio,
    const void* __restrict__ g, const void* __restrict__ bta,
    const int* __restrict__ flag) {
    const int f32 = flag[0];
    const int r = blockIdx.x;
    const int b = (r >= 4095) ? 1 : 0;
    const int s = r - b * 4095;
    const size_t xrow = (size_t)r * 512;
    const size_t hrow = ((size_t)b * 4096 + s) * 512;
    const int t = threadIdx.x;
    float h0 = rdIn(x, xrow + t, f32) + bf2f(hio[hrow + t]);
    float h1 = rdIn(x, xrow + 256 + t, f32) + bf2f(hio[hrow + 256 + t]);
    float sum = h0 + h1, sq = h0 * h0 + h1 * h1;
#pragma unroll
    for (int off = 1; off < 64; off <<= 1) {
        sum += __shfl_xor(sum, off, 64);
        sq += __shfl_xor(sq, off, 64);
    }
    __shared__ float red[8];
    int wave = t >> 6, lane = t & 63;
    if (lane == 0) { red[wave] = sum; red[wave + 4] = sq; }
    __syncthreads();
    sum = red[0] + red[1] + red[2] + red[3];
    sq = red[4] + red[5] + red[6] + red[7];
    float mu = sum * (1.f / 512.f);
    float var = sq * (1.f / 512.f) - mu * mu;
    float rs = rsqrtf(var + 1e-5f);
    float v0 = (h0 - mu) * rs * rdIn(g, t, f32) + rdIn(bta, t, f32);
    float v1 = (h1 - mu) * rs * rdIn(g, 256 + t, f32) + rdIn(bta, 256 + t, f32);
    hio[hrow + t] = f2bf(v0);
    hio[hrow + 256 + t] = f2bf(v1);
}

// ---------------- launch -----------------------------------------------------
// ws layout (peak 47,710,212 B; ws_size proven >= this in rounds 5-9):
//   Qb[0) Kb[8.39M) Vb[16.78M)
//   Xp[33.55M..41.94M)  bf16 x, dead after QKV GEMM
//   Gs[8.39M..41.94M)   MLP strip, written after Xp is dead
//   Wqt[41.94M) W1t[43.52M) W2t[45.61M) flag[47.71M)
extern "C" void kernel_launch(void* const* d_in, const int* in_sizes, int n_in,
                              void* d_out, int out_size, void* d_ws, size_t ws_size,
                              hipStream_t stream) {
    const void* x   = d_in[0];
    const void* Wq  = d_in[2];
    const void* bq  = d_in[3];
    const void* Wk  = d_in[4];
    const void* bk  = d_in[5];
    const void* Wv  = d_in[6];
    const void* bv  = d_in[7];
    const void* lng = d_in[14];
    const void* lnb = d_in[15];
    const void* W1  = d_in[16];
    const void* b1  = d_in[17];
    const void* W2  = d_in[18];
    const void* b2  = d_in[19];

    char* ws = (char*)d_ws;
    ushort_t* Qb  = (ushort_t*)(ws + 0);
    ushort_t* Kb  = (ushort_t*)(ws + 8388608);
    ushort_t* Vb  = (ushort_t*)(ws + 16777216);
    ushort_t* Xp  = (ushort_t*)(ws + 33554432);
    ushort_t* Gs  = (ushort_t*)(ws + 8388608);
    ushort_t* Wqt = (ushort_t*)(ws + 41943040);
    ushort_t* W1t = (ushort_t*)(ws + 43515904);
    ushort_t* W2t = (ushort_t*)(ws + 45613056);
    int*      flg = (int*)(ws + 47710208);

    detect_kernel<<<dim3(1), dim3(256), 0, stream>>>((const ushort_t*)x, flg);

    transpose_kernel<<<dim3(16, 16, 3), dim3(256), 0, stream>>>(Wq, Wk, Wv, Wqt, 512, 512, flg);
    transpose_kernel<<<dim3(64, 16, 1), dim3(256), 0, stream>>>(W1, W1, W1, W1t, 512, 2048, flg);
    transpose_kernel<<<dim3(16, 64, 1), dim3(256), 0, stream>>>(W2, W2, W2, W2t, 2048, 512, flg);

    prep_kernel<<<dim3(2048), dim3(256), 0, stream>>>(x, Xp, flg);

    const float scale = 0.125f;  // 1/sqrt(64)
    gemm_bt_kernel<128><<<dim3(64, 12), dim3(256), 0, stream>>>(
        Xp, Wqt, bq, bk, bv, Qb, 8192, 1536, 512, scale, 3, nullptr, flg);

    attn_mfma_kernel<<<dim3(1024), dim3(256), 0, stream>>>(Qb, Kb, Vb);

    ln_kernel<<<dim3(8190), dim3(256), 0, stream>>>(x, Qb, lng, lnb, flg);

    gemm_bt_kernel<128><<<dim3(64, 16), dim3(256), 0, stream>>>(
        Qb, W1t, b1, b1, b1, Gs, 8192, 2048, 512, 1.0f, 1, nullptr, flg);
    gemm_bt_kernel<64><<<dim3(64, 8), dim3(256), 0, stream>>>(
        Gs, W2t, b2, b2, b2, d_out, 8192, 512, 2048, 1.0f, 2, Qb, flg);
}

// Round 11
// 302.118 us; speedup vs baseline: 6.2532x; 6.2532x over previous
//
#include <hip/hip_runtime.h>
#include <math.h>

typedef unsigned short ushort_t;
typedef __attribute__((ext_vector_type(4))) float floatx4;
typedef __attribute__((ext_vector_type(8))) short shortx8;
typedef __attribute__((ext_vector_type(8))) unsigned short ushortx8;

__device__ __forceinline__ float bf2f(ushort_t h) {
    union { unsigned u; float f; } x; x.u = ((unsigned)h) << 16; return x.f;
}
__device__ __forceinline__ ushort_t f2bf(float f) {
    union { float f; unsigned u; } x; x.f = f;
    unsigned r = x.u + 0x7fffu + ((x.u >> 16) & 1u);
    return (ushort_t)(r >> 16);
}
__device__ __forceinline__ float rdIn(const void* p, size_t i, int f32) {
    return f32 ? ((const float*)p)[i] : bf2f(((const ushort_t*)p)[i]);
}
// async global->LDS DMA, 16 B per lane (dest = wave-uniform base + lane*16)
__device__ __forceinline__ void gload16(const ushort_t* g, ushort_t* l) {
    __builtin_amdgcn_global_load_lds(
        (const __attribute__((address_space(1))) unsigned int*)g,
        (__attribute__((address_space(3))) unsigned int*)l, 16, 0, 0);
}
// branch-free GELU: erf via Abramowitz-Stegun 7.1.26 (|erf err| <= 1.5e-7)
__device__ __forceinline__ float gelu_f(float v) {
    float z = fabsf(v) * 0.70710678118654752f;
    float t = __builtin_amdgcn_rcpf(1.0f + 0.3275911f * z);
    float p = 1.061405429f;
    p = p * t - 1.453152027f;
    p = p * t + 1.421413741f;
    p = p * t - 0.284496736f;
    p = p * t + 0.254829592f;
    p = p * t;
    float er = 1.0f - p * __expf(-z * z);
    er = copysignf(er, v);
    return 0.5f * v * (1.0f + er);
}

// ---------------- dtype detect: bf16 vs fp32 --------------------------------
__global__ __launch_bounds__(256) void detect_kernel(const ushort_t* __restrict__ x,
                                                     int* __restrict__ flag) {
    __shared__ int cnt;
    if (threadIdx.x == 0) cnt = 0;
    __syncthreads();
    ushort_t v = x[threadIdx.x];
    int e = (v >> 7) & 0xff;
    int ok = (e >= 100 && e <= 150) || (v == 0);
    atomicAdd(&cnt, ok);
    __syncthreads();
    if (threadIdx.x == 0) flag[0] = (cnt >= 240) ? 0 : 1;   // 0=bf16, 1=fp32
}

// ---------------- prep: x [2,4095,512] raw -> Xp [2,4096,512] bf16 ----------
__global__ __launch_bounds__(256) void prep_kernel(const void* __restrict__ x,
                                                   ushort_t* __restrict__ Xp,
                                                   const int* __restrict__ flag) {
    const int f32 = flag[0];
    int i = blockIdx.x * 256 + threadIdx.x;
    int e = i * 8;
    int s = (e >> 9) & 4095;
    int b = e >> 21;
    ushortx8 val = {0, 0, 0, 0, 0, 0, 0, 0};
    if (s < 4095) {
        size_t src = ((size_t)(b * 4095 + s) << 9) + (e & 511);
        if (f32) {
            const float* p = (const float*)x + src;
            floatx4 a = *(const floatx4*)p;
            floatx4 c = *(const floatx4*)(p + 4);
            val[0] = f2bf(a[0]); val[1] = f2bf(a[1]); val[2] = f2bf(a[2]); val[3] = f2bf(a[3]);
            val[4] = f2bf(c[0]); val[5] = f2bf(c[1]); val[6] = f2bf(c[2]); val[7] = f2bf(c[3]);
        } else {
            val = *(const ushortx8*)((const ushort_t*)x + src);
        }
    }
    *(ushortx8*)&Xp[e] = val;
}

// ---------------- transpose raw weight [R,C] -> bf16 [C,R] ------------------
__global__ __launch_bounds__(256) void transpose_kernel(
    const void* __restrict__ in0, const void* __restrict__ in1,
    const void* __restrict__ in2, ushort_t* __restrict__ out,
    int R, int C, const int* __restrict__ flag) {
    const int f32 = flag[0];
    const int z = blockIdx.z;
    const void* in = (z == 0) ? in0 : (z == 1) ? in1 : in2;
    __shared__ ushort_t tile[32][33];
    int c0 = blockIdx.x * 32, r0 = blockIdx.y * 32;
    int tx = threadIdx.x & 31, ty = threadIdx.x >> 5;
#pragma unroll
    for (int i = 0; i < 4; i++) {
        size_t idx = (size_t)(r0 + ty + 8 * i) * C + c0 + tx;
        tile[ty + 8 * i][tx] = f32 ? f2bf(((const float*)in)[idx])
                                   : ((const ushort_t*)in)[idx];
    }
    __syncthreads();
#pragma unroll
    for (int i = 0; i < 4; i++)
        out[(size_t)z * R * C + (size_t)(c0 + ty + 8 * i) * R + r0 + tx] =
            tile[tx][ty + 8 * i];
}

// ---------------- GEMM epilogue (shared) ------------------------------------
__device__ __forceinline__ void gemm_epilogue(
    float v, int m, int n, int N, float scale, int epi,
    const void* bias0, const void* bias1, const void* bias2,
    void* outp, const ushort_t* resid, int f32) {
    if (epi == 3) {
        int idx = n >> 9, off = n & 511;
        const void* bp = (idx == 0) ? bias0 : (idx == 1) ? bias1 : bias2;
        float bb = rdIn(bp, off, f32);
        float sc = (idx == 0) ? scale : 1.0f;
        ((ushort_t*)outp)[(size_t)idx * 4194304 + (size_t)m * 512 + off] =
            f2bf((v + bb) * sc);
    } else if (epi == 1) {
        v += rdIn(bias0, n, f32);
        ((ushort_t*)outp)[(size_t)m * N + n] = f2bf(gelu_f(v));
    } else {
        int bb2 = m >> 12, s = m & 4095;
        if (s < 4095) {
            v += rdIn(bias0, n, f32) + bf2f(resid[(size_t)m * N + n]);
            size_t oidx = ((size_t)bb2 * 4095 + s) * (size_t)N + n;
            if (f32) ((float*)outp)[oidx] = v;
            else     ((ushort_t*)outp)[oidx] = f2bf(v);
        }
    }
}

// ---------------- GEMM: 128xTBN tile, 4 waves, DMA double-buffer (R7) -------
#define BM 128
#define BK 32

template<int TBN>
__global__ __launch_bounds__(256) void gemm_bt_kernel(
    const ushort_t* __restrict__ A, const ushort_t* __restrict__ Bt,
    const void* __restrict__ bias0, const void* __restrict__ bias1,
    const void* __restrict__ bias2, void* outp,
    int M, int N, int K, float scale, int epi,
    const ushort_t* __restrict__ resid, const int* __restrict__ flag) {
    constexpr int TN = TBN / 32;
    const int f32 = flag[0];
    __shared__ __align__(16) ushort_t As[2][BM][BK];
    __shared__ __align__(16) ushort_t Bs[2][TBN][BK];
    const int m0 = blockIdx.x * BM, n0 = blockIdx.y * TBN;
    const int t = threadIdx.x;
    const int lane = t & 63, wave = t >> 6;
    const int wr = wave >> 1, wc = wave & 1;
    const int quad = lane >> 4, l16 = lane & 15;
    const int srow = t >> 2, schunk = (t & 3) * 8;

    const ushort_t* Ag = A + (size_t)(m0 + srow) * K + schunk;
    const ushort_t* Bg = Bt + (size_t)(n0 + srow) * K + schunk;

    floatx4 acc[4][TN];
#pragma unroll
    for (int i = 0; i < 4; i++)
#pragma unroll
        for (int j = 0; j < TN; j++)
#pragma unroll
            for (int r = 0; r < 4; r++) acc[i][j][r] = 0.f;

    gload16(Ag,                  &As[0][srow][schunk]);
    gload16(Ag + (size_t)64 * K, &As[0][srow + 64][schunk]);
    gload16(Bg,                  &Bs[0][srow][schunk]);
    if (TBN == 128)
        gload16(Bg + (size_t)64 * K, &Bs[0][srow + 64][schunk]);

    const int KT = K / BK;
    for (int kt = 0; kt < KT; kt++) {
        __syncthreads();
        if (kt + 1 < KT) {
            int nb = (kt + 1) & 1;
            const ushort_t* Ag2 = Ag + (kt + 1) * BK;
            const ushort_t* Bg2 = Bg + (kt + 1) * BK;
            gload16(Ag2,                  &As[nb][srow][schunk]);
            gload16(Ag2 + (size_t)64 * K, &As[nb][srow + 64][schunk]);
            gload16(Bg2,                  &Bs[nb][srow][schunk]);
            if (TBN == 128)
                gload16(Bg2 + (size_t)64 * K, &Bs[nb][srow + 64][schunk]);
        }
        const int cb = kt & 1;
        shortx8 af[4], bfr[TN];
#pragma unroll
        for (int tm = 0; tm < 4; tm++)
            af[tm] = *(const shortx8*)&As[cb][wr * 64 + tm * 16 + l16][quad * 8];
#pragma unroll
        for (int tn = 0; tn < TN; tn++)
            bfr[tn] = *(const shortx8*)&Bs[cb][wc * (TBN / 2) + tn * 16 + l16][quad * 8];
#pragma unroll
        for (int tm = 0; tm < 4; tm++)
#pragma unroll
            for (int tn = 0; tn < TN; tn++)
                acc[tm][tn] = __builtin_amdgcn_mfma_f32_16x16x32_bf16(
                    af[tm], bfr[tn], acc[tm][tn], 0, 0, 0);
    }

#pragma unroll
    for (int tm = 0; tm < 4; tm++)
#pragma unroll
        for (int tn = 0; tn < TN; tn++)
#pragma unroll
            for (int r = 0; r < 4; r++)
                gemm_epilogue(acc[tm][tn][r],
                              m0 + wr * 64 + tm * 16 + quad * 4 + r,
                              n0 + wc * (TBN / 2) + tn * 16 + l16,
                              N, scale, epi, bias0, bias1, bias2, outp, resid, f32);
}

// ---------------- GEMM BK=64: 128x64 tile, halved K-chain (down-GEMM) -------
// Same structure/fragment layout as gemm_bt_kernel<64>, but 64-wide K-tiles:
// 32 barrier iterations instead of 64 for K=2048. LDS 48 KB -> 3 blocks/CU.
__global__ __launch_bounds__(256) void gemm_bk64_kernel(
    const ushort_t* __restrict__ A, const ushort_t* __restrict__ Bt,
    const void* __restrict__ bias0, void* outp,
    int M, int N, int K, int epi,
    const ushort_t* __restrict__ resid, const int* __restrict__ flag) {
    const int f32 = flag[0];
    __shared__ __align__(16) ushort_t As[2][128][64];
    __shared__ __align__(16) ushort_t Bs[2][64][64];
    const int m0 = blockIdx.x * 128, n0 = blockIdx.y * 64;
    const int t = threadIdx.x;
    const int lane = t & 63, wave = t >> 6;
    const int wr = wave >> 1, wc = wave & 1;     // 2x2 waves, each 64 rows x 32 cols
    const int quad = lane >> 4, l16 = lane & 15;
    const int srow = t >> 3, schunk = (t & 7) * 8;   // srow 0..31, 64B rows

    // A: 4 DMA calls cover rows 0..127; B: 2 calls cover rows 0..63
    const ushort_t* Ag = A + (size_t)(m0 + srow) * K + schunk;
    const ushort_t* Bg = Bt + (size_t)(n0 + srow) * K + schunk;

    floatx4 acc[4][2];
#pragma unroll
    for (int i = 0; i < 4; i++)
#pragma unroll
        for (int j = 0; j < 2; j++)
#pragma unroll
            for (int r = 0; r < 4; r++) acc[i][j][r] = 0.f;

#define STAGE64(buf, kofs)                                                   \
    do {                                                                     \
        gload16(Ag + (kofs),                    &As[buf][srow][schunk]);     \
        gload16(Ag + (kofs) + (size_t)32 * K,   &As[buf][srow + 32][schunk]);\
        gload16(Ag + (kofs) + (size_t)64 * K,   &As[buf][srow + 64][schunk]);\
        gload16(Ag + (kofs) + (size_t)96 * K,   &As[buf][srow + 96][schunk]);\
        gload16(Bg + (kofs),                    &Bs[buf][srow][schunk]);     \
        gload16(Bg + (kofs) + (size_t)32 * K,   &Bs[buf][srow + 32][schunk]);\
    } while (0)

    STAGE64(0, 0);

    const int KT = K / 64;
    for (int kt = 0; kt < KT; kt++) {
        __syncthreads();
        if (kt + 1 < KT) STAGE64((kt + 1) & 1, (size_t)(kt + 1) * 64);
        const int cb = kt & 1;
#pragma unroll
        for (int ks = 0; ks < 2; ks++) {
            shortx8 af[4], bfr[2];
#pragma unroll
            for (int tm = 0; tm < 4; tm++)
                af[tm] = *(const shortx8*)&As[cb][wr * 64 + tm * 16 + l16][ks * 32 + quad * 8];
#pragma unroll
            for (int tn = 0; tn < 2; tn++)
                bfr[tn] = *(const shortx8*)&Bs[cb][wc * 32 + tn * 16 + l16][ks * 32 + quad * 8];
#pragma unroll
            for (int tm = 0; tm < 4; tm++)
#pragma unroll
                for (int tn = 0; tn < 2; tn++)
                    acc[tm][tn] = __builtin_amdgcn_mfma_f32_16x16x32_bf16(
                        af[tm], bfr[tn], acc[tm][tn], 0, 0, 0);
        }
    }
#undef STAGE64

#pragma unroll
    for (int tm = 0; tm < 4; tm++)
#pragma unroll
        for (int tn = 0; tn < 2; tn++)
#pragma unroll
            for (int r = 0; r < 4; r++)
                gemm_epilogue(acc[tm][tn][r],
                              m0 + wr * 64 + tm * 16 + quad * 4 + r,
                              n0 + wc * 32 + tn * 16 + l16,
                              N, 1.0f, epi, bias0, bias0, bias0, outp, resid, f32);
}

// ---------------- MFMA windowed attention + global key ----------------------
#define ALD 344

__global__ __launch_bounds__(256) void attn_mfma_kernel(
    ushort_t* Q, const ushort_t* __restrict__ Kx, const ushort_t* __restrict__ Vx) {
    __shared__ ushort_t Pl[64][ALD];
    __shared__ ushort_t Vt[2][64][40];
    __shared__ float pgl[64];

    const int t = threadIdx.x;
    const int lane = t & 63, w = t >> 6;
    const int l16 = lane & 15, quad = lane >> 4;
    const int bid = blockIdx.x;
    const int qt = bid & 63;
    const int h = (bid >> 6) & 7;
    const int b = bid >> 9;
    const int q0 = qt * 64;
    const int jmin = q0 - 128;
    const size_t base = ((size_t)b * 4096) * 512 + (size_t)h * 64;

    const int qw = q0 + w * 16;
    const int lo = qw - 128, hi = qw + 15 + 128;

    shortx8 qf0, qf1;
    {
        const ushort_t* qp = Q + base + (size_t)(qw + l16) * 512 + quad * 8;
        qf0 = *(const shortx8*)(qp);
        qf1 = *(const shortx8*)(qp + 32);
    }

    floatx4 s[21];
#pragma unroll
    for (int i = 0; i < 21; i++)
#pragma unroll
        for (int r = 0; r < 4; r++) s[i][r] = 0.f;

#pragma unroll
    for (int tt = 0; tt < 20; tt++) {
        int jt = jmin + tt * 16;
        if (jt + 15 < lo || jt > hi) continue;
        int key = jt + l16;
        int kcl = min(max(key, 0), 4094);
        const ushort_t* kp = Kx + base + (size_t)kcl * 512 + quad * 8;
        shortx8 k0 = *(const shortx8*)(kp);
        shortx8 k1 = *(const shortx8*)(kp + 32);
        s[tt] = __builtin_amdgcn_mfma_f32_16x16x32_bf16(qf0, k0, s[tt], 0, 0, 0);
        s[tt] = __builtin_amdgcn_mfma_f32_16x16x32_bf16(qf1, k1, s[tt], 0, 0, 0);
    }
    {
        const ushort_t* kp = Kx + base + (size_t)4095 * 512 + quad * 8;
        shortx8 k0 = *(const shortx8*)(kp);
        shortx8 k1 = *(const shortx8*)(kp + 32);
        s[20] = __builtin_amdgcn_mfma_f32_16x16x32_bf16(qf0, k0, s[20], 0, 0, 0);
        s[20] = __builtin_amdgcn_mfma_f32_16x16x32_bf16(qf1, k1, s[20], 0, 0, 0);
    }

#pragma unroll
    for (int tt = 0; tt < 20; tt++) {
        int j = jmin + tt * 16 + l16;
        bool okj = (j >= 0) && (j <= 4094);
#pragma unroll
        for (int r = 0; r < 4; r++) {
            int q = qw + quad * 4 + r;
            bool ok = okj && (j - q <= 128) && (q - j <= 128);
            if (!ok) s[tt][r] = -1e30f;
        }
    }
    if (l16 != 0) {
#pragma unroll
        for (int r = 0; r < 4; r++) s[20][r] = -1e30f;
    }

    floatx4 mx = s[0];
#pragma unroll
    for (int tt = 1; tt < 21; tt++)
#pragma unroll
        for (int r = 0; r < 4; r++) mx[r] = fmaxf(mx[r], s[tt][r]);
#pragma unroll
    for (int off = 1; off < 16; off <<= 1)
#pragma unroll
        for (int r = 0; r < 4; r++) mx[r] = fmaxf(mx[r], __shfl_xor(mx[r], off, 64));

    floatx4 sum;
#pragma unroll
    for (int r = 0; r < 4; r++) sum[r] = 0.f;
#pragma unroll
    for (int tt = 0; tt < 21; tt++)
#pragma unroll
        for (int r = 0; r < 4; r++) {
            float e = __expf(s[tt][r] - mx[r]);
            s[tt][r] = e;
            sum[r] += e;
        }
#pragma unroll
    for (int off = 1; off < 16; off <<= 1)
#pragma unroll
        for (int r = 0; r < 4; r++) sum[r] += __shfl_xor(sum[r], off, 64);

    floatx4 inv;
#pragma unroll
    for (int r = 0; r < 4; r++) inv[r] = 1.f / sum[r];

#pragma unroll
    for (int tt = 0; tt < 20; tt++)
#pragma unroll
        for (int r = 0; r < 4; r++)
            Pl[w * 16 + quad * 4 + r][tt * 16 + l16] = f2bf(s[tt][r]);
    if (l16 == 0) {
#pragma unroll
        for (int r = 0; r < 4; r++) pgl[w * 16 + quad * 4 + r] = s[20][r];
    }

    floatx4 o[4];
#pragma unroll
    for (int nt = 0; nt < 4; nt++)
#pragma unroll
        for (int r = 0; r < 4; r++) o[nt][r] = 0.f;

    const int ck = t & 31, cd = t >> 5;
    ushortx8 vreg;
    {
        int row = min(max(jmin + ck, 0), 4095);
        vreg = *(const ushortx8*)&Vx[base + (size_t)row * 512 + cd * 8];
    }
    for (int c = 0; c < 10; c++) {
#pragma unroll
        for (int e = 0; e < 8; e++) Vt[c & 1][cd * 8 + e][ck] = vreg[e];
        if (c < 9) {
            int row = min(max(jmin + (c + 1) * 32 + ck, 0), 4095);
            vreg = *(const ushortx8*)&Vx[base + (size_t)row * 512 + cd * 8];
        }
        __syncthreads();
        int jc = jmin + c * 32;
        if (jc + 31 >= lo && jc <= hi) {
            shortx8 pf = *(const shortx8*)&Pl[w * 16 + l16][c * 32 + quad * 8];
#pragma unroll
            for (int nt = 0; nt < 4; nt++) {
                shortx8 vf = *(const shortx8*)&Vt[c & 1][nt * 16 + l16][quad * 8];
                o[nt] = __builtin_amdgcn_mfma_f32_16x16x32_bf16(pf, vf, o[nt], 0, 0, 0);
            }
        }
    }

#pragma unroll
    for (int nt = 0; nt < 4; nt++) {
        float vg = bf2f(Vx[base + (size_t)4095 * 512 + nt * 16 + l16]);
#pragma unroll
        for (int r = 0; r < 4; r++) {
            float pg = pgl[w * 16 + quad * 4 + r];
            float val = (o[nt][r] + pg * vg) * inv[r];
            Q[base + (size_t)(qw + quad * 4 + r) * 512 + nt * 16 + l16] = f2bf(val);
        }
    }
}

// ---------------- residual + LayerNorm, in-place on hio ---------------------
__global__ __launch_bounds__(256) void ln_kernel(
    const void* __restrict__ x, ushort_t* hio,
    const void* __restrict__ g, const void* __restrict__ bta,
    const int* __restrict__ flag) {
    const int f32 = flag[0];
    const int r = blockIdx.x;
    const int b = (r >= 4095) ? 1 : 0;
    const int s = r - b * 4095;
    const size_t xrow = (size_t)r * 512;
    const size_t hrow = ((size_t)b * 4096 + s) * 512;
    const int t = threadIdx.x;
    float h0 = rdIn(x, xrow + t, f32) + bf2f(hio[hrow + t]);
    float h1 = rdIn(x, xrow + 256 + t, f32) + bf2f(hio[hrow + 256 + t]);
    float sum = h0 + h1, sq = h0 * h0 + h1 * h1;
#pragma unroll
    for (int off = 1; off < 64; off <<= 1) {
        sum += __shfl_xor(sum, off, 64);
        sq += __shfl_xor(sq, off, 64);
    }
    __shared__ float red[8];
    int wave = t >> 6, lane = t & 63;
    if (lane == 0) { red[wave] = sum; red[wave + 4] = sq; }
    __syncthreads();
    sum = red[0] + red[1] + red[2] + red[3];
    sq = red[4] + red[5] + red[6] + red[7];
    float mu = sum * (1.f / 512.f);
    float var = sq * (1.f / 512.f) - mu * mu;
    float rs = rsqrtf(var + 1e-5f);
    float v0 = (h0 - mu) * rs * rdIn(g, t, f32) + rdIn(bta, t, f32);
    float v1 = (h1 - mu) * rs * rdIn(g, 256 + t, f32) + rdIn(bta, 256 + t, f32);
    hio[hrow + t] = f2bf(v0);
    hio[hrow + 256 + t] = f2bf(v1);
}

// ---------------- launch -----------------------------------------------------
// ws layout (peak 47,710,212 B; ws_size proven >= this in rounds 5-10):
//   Qb[0) Kb[8.39M) Vb[16.78M)
//   Xp[33.55M..41.94M)  bf16 x, dead after QKV GEMM
//   Gs[8.39M..41.94M)   MLP strip, written after Xp is dead
//   Wqt[41.94M) W1t[43.52M) W2t[45.61M) flag[47.71M)
extern "C" void kernel_launch(void* const* d_in, const int* in_sizes, int n_in,
                              void* d_out, int out_size, void* d_ws, size_t ws_size,
                              hipStream_t stream) {
    const void* x   = d_in[0];
    const void* Wq  = d_in[2];
    const void* bq  = d_in[3];
    const void* Wk  = d_in[4];
    const void* bk  = d_in[5];
    const void* Wv  = d_in[6];
    const void* bv  = d_in[7];
    const void* lng = d_in[14];
    const void* lnb = d_in[15];
    const void* W1  = d_in[16];
    const void* b1  = d_in[17];
    const void* W2  = d_in[18];
    const void* b2  = d_in[19];

    char* ws = (char*)d_ws;
    ushort_t* Qb  = (ushort_t*)(ws + 0);
    ushort_t* Kb  = (ushort_t*)(ws + 8388608);
    ushort_t* Vb  = (ushort_t*)(ws + 16777216);
    ushort_t* Xp  = (ushort_t*)(ws + 33554432);
    ushort_t* Gs  = (ushort_t*)(ws + 8388608);
    ushort_t* Wqt = (ushort_t*)(ws + 41943040);
    ushort_t* W1t = (ushort_t*)(ws + 43515904);
    ushort_t* W2t = (ushort_t*)(ws + 45613056);
    int*      flg = (int*)(ws + 47710208);

    detect_kernel<<<dim3(1), dim3(256), 0, stream>>>((const ushort_t*)x, flg);

    transpose_kernel<<<dim3(16, 16, 3), dim3(256), 0, stream>>>(Wq, Wk, Wv, Wqt, 512, 512, flg);
    transpose_kernel<<<dim3(64, 16, 1), dim3(256), 0, stream>>>(W1, W1, W1, W1t, 512, 2048, flg);
    transpose_kernel<<<dim3(16, 64, 1), dim3(256), 0, stream>>>(W2, W2, W2, W2t, 2048, 512, flg);

    prep_kernel<<<dim3(2048), dim3(256), 0, stream>>>(x, Xp, flg);

    const float scale = 0.125f;  // 1/sqrt(64)
    gemm_bt_kernel<128><<<dim3(64, 12), dim3(256), 0, stream>>>(
        Xp, Wqt, bq, bk, bv, Qb, 8192, 1536, 512, scale, 3, nullptr, flg);

    attn_mfma_kernel<<<dim3(1024), dim3(256), 0, stream>>>(Qb, Kb, Vb);

    ln_kernel<<<dim3(8190), dim3(256), 0, stream>>>(x, Qb, lng, lnb, flg);

    gemm_bt_kernel<128><<<dim3(64, 16), dim3(256), 0, stream>>>(
        Qb, W1t, b1, b1, b1, Gs, 8192, 2048, 512, 1.0f, 1, nullptr, flg);
    gemm_bk64_kernel<<<dim3(64, 8), dim3(256), 0, stream>>>(
        Gs, W2t, b2, d_out, 8192, 512, 2048, 2, Qb, flg);
}